// Round 1
// baseline (387.354 us; speedup 1.0000x reference)
//
#include <hip/hip_runtime.h>

// Output tile 64x64, input tile 36x36 (32 + 4 halo for the 4-tap bicubic).
constexpr int OT  = 64;
constexpr int IT  = 36;
constexpr int ITP = 37;   // +1 pad

// Monotone float <-> ordered-uint map for atomic min/max on floats.
__device__ __forceinline__ unsigned f2ord(float f) {
    unsigned u = __float_as_uint(f);
    return (u & 0x80000000u) ? ~u : (u | 0x80000000u);
}
__device__ __forceinline__ float ord2f(unsigned o) {
    unsigned u = (o & 0x80000000u) ? (o ^ 0x80000000u) : ~o;
    return __uint_as_float(u);
}

// Bicubic (a = -0.75) x2-upsample phase weights, src = 0.5*i - 0.25:
//  even i: taps at j0-2..j0+1, weights w(1.75), w(0.75), w(0.25), w(1.25)
//  odd  i: taps at j0-1..j0+2, weights reversed.
#define W0 (-0.03515625f)
#define W1 ( 0.26171875f)
#define W2 ( 0.87890625f)
#define W3 (-0.10546875f)

// MODE 0: global min/max reduction over upsampled values.
// MODE 1: recompute, normalize (v - min) / (max - min), write out.
template <int MODE>
__global__ __launch_bounds__(256)
void qwt_up2(const float* __restrict__ LL,
             float* __restrict__ out,
             unsigned* __restrict__ minmax)
{
    __shared__ float sIn[IT][ITP];   // clamped input tile
    __shared__ float sT[IT][OT];     // horizontally-upsampled intermediate

    const int t  = threadIdx.x;
    const int tx = blockIdx.x;       // 0..7 tile col
    const int ty = blockIdx.y;       // 0..7 tile row
    const int pl = blockIdx.z;       // 0..63 plane = b*8 + ch
    const int b  = pl >> 3;
    const int ch = pl & 7;

    // lglg block = LL[:, 0:8] of the (8,32,256,256) tensor
    const float* __restrict__ src = LL + (size_t)(b * 32 + ch) * (256 * 256);

    const int R0   = ty * OT;        // output row base
    const int C0   = tx * OT;        // output col base
    const int rin0 = (R0 >> 1) - 2;  // input row of tile-local 0
    const int cin0 = (C0 >> 1) - 2;

    // Load 36x36 input tile with clamp-to-edge (matches jnp.clip(pos,0,n-1)).
    for (int idx = t; idx < IT * IT; idx += 256) {
        int r  = idx / IT;
        int cc = idx - r * IT;
        int gr = min(max(rin0 + r, 0), 255);
        int gc = min(max(cin0 + cc, 0), 255);
        sIn[r][cc] = src[gr * 256 + gc];
    }
    __syncthreads();

    // Horizontal upsample: sT[r][c] for r in [0,36), c in [0,64)
    {
        const int  cc   = t & 63;
        const bool odd  = cc & 1;
        const int  base = (cc >> 1) + (odd ? 1 : 0);
        const float a0 = odd ? W3 : W0;
        const float a1 = odd ? W2 : W1;
        const float a2 = odd ? W1 : W2;
        const float a3 = odd ? W0 : W3;
        for (int r = (t >> 6); r < IT; r += 4) {
            sT[r][cc] = a0 * sIn[r][base]     + a1 * sIn[r][base + 1]
                      + a2 * sIn[r][base + 2] + a3 * sIn[r][base + 3];
        }
    }
    __syncthreads();

    const int j = t & 63;
    float vmin = 1e30f, vmax = -1e30f;
    float mn = 0.f, scale = 1.f;
    if (MODE == 1) {
        mn = ord2f(minmax[0]);
        float mx = ord2f(minmax[1]);
        scale = 1.0f / (mx - mn);
    }
    float* dst = (MODE == 1)
        ? out + (size_t)pl * (512 * 512) + (size_t)R0 * 512 + C0 + j
        : nullptr;

    // Vertical upsample: 16 output rows per thread (rows t>>6, +4 ...)
    for (int i = (t >> 6); i < OT; i += 4) {
        const bool odd  = i & 1;
        const int  base = (i >> 1) + (odd ? 1 : 0);
        const float a0 = odd ? W3 : W0;
        const float a1 = odd ? W2 : W1;
        const float a2 = odd ? W1 : W2;
        const float a3 = odd ? W0 : W3;
        float v = a0 * sT[base][j]     + a1 * sT[base + 1][j]
                + a2 * sT[base + 2][j] + a3 * sT[base + 3][j];
        if (MODE == 0) {
            vmin = fminf(vmin, v);
            vmax = fmaxf(vmax, v);
        } else {
            dst[(size_t)i * 512] = (v - mn) * scale;
        }
    }

    if (MODE == 0) {
        // wave-64 butterfly reduce, then cross-wave via LDS, then one atomic pair
        for (int off = 32; off > 0; off >>= 1) {
            vmin = fminf(vmin, __shfl_down(vmin, off, 64));
            vmax = fmaxf(vmax, __shfl_down(vmax, off, 64));
        }
        __shared__ float wmn[4], wmx[4];
        const int wave = t >> 6;
        if ((t & 63) == 0) { wmn[wave] = vmin; wmx[wave] = vmax; }
        __syncthreads();
        if (t == 0) {
            float m = fminf(fminf(wmn[0], wmn[1]), fminf(wmn[2], wmn[3]));
            float M = fmaxf(fmaxf(wmx[0], wmx[1]), fmaxf(wmx[2], wmx[3]));
            atomicMin(&minmax[0], f2ord(m));
            atomicMax(&minmax[1], f2ord(M));
        }
    }
}

extern "C" void kernel_launch(void* const* d_in, const int* in_sizes, int n_in,
                              void* d_out, int out_size, void* d_ws, size_t ws_size,
                              hipStream_t stream)
{
    (void)in_sizes; (void)n_in; (void)out_size; (void)ws_size;
    const float* LL = (const float*)d_in[0];
    float* out      = (float*)d_out;
    unsigned* minmax = (unsigned*)d_ws;

    // ws is re-poisoned to 0xAA before every timed launch: init atomic slots.
    // min slot -> 0xFFFFFFFF (max ordered uint), max slot -> 0x00000000.
    hipMemsetAsync(minmax, 0xFF, 4, stream);
    hipMemsetAsync((char*)d_ws + 4, 0x00, 4, stream);

    dim3 grid(8, 8, 64);
    dim3 block(256);
    qwt_up2<0><<<grid, block, 0, stream>>>(LL, nullptr, minmax);
    qwt_up2<1><<<grid, block, 0, stream>>>(LL, out, minmax);
}

// Round 2
// 301.041 us; speedup vs baseline: 1.2867x; 1.2867x over previous
//
#include <hip/hip_runtime.h>

// Output tile 64x64 per block, input tile 36x36 (32 + 4 halo for 4-tap bicubic).
constexpr int OT  = 64;
constexpr int IT  = 36;
constexpr int ITP = 37;   // sIn row stride (+1 pad)
constexpr int STP = 68;   // sT row stride in floats: 16B-aligned, non-pow2 bank stride

// Bicubic (a = -0.75) x2-upsample phase weights, src = 0.5*i - 0.25.
#define W0 (-0.03515625f)
#define W1 ( 0.26171875f)
#define W2 ( 0.87890625f)
#define W3 (-0.10546875f)

// MODE 0: compute tiles, write per-block min/max partials.
// MODE 1: recompute tiles, normalize with res[0]=min, res[1]=1/(max-min), store.
template <int MODE>
__global__ __launch_bounds__(256)
void qwt_up2(const float* __restrict__ LL,
             float* __restrict__ out,
             float* __restrict__ pmin,
             float* __restrict__ pmax,
             const float* __restrict__ res)
{
    __shared__ float sIn[IT][ITP];   // clamped input tile
    __shared__ float sT[IT][STP];    // horizontally-upsampled intermediate

    const int t  = threadIdx.x;
    const int tx = blockIdx.x;       // 0..7 tile col
    const int ty = blockIdx.y;       // 0..7 tile row
    const int pl = blockIdx.z;       // 0..63 plane = b*8 + ch
    const int b  = pl >> 3;
    const int ch = pl & 7;

    // lglg block = LL[:, 0:8] of the (8,32,256,256) tensor
    const float* __restrict__ src = LL + (size_t)(b * 32 + ch) * (256 * 256);

    const int R0   = ty * OT;
    const int C0   = tx * OT;
    const int rin0 = (R0 >> 1) - 2;
    const int cin0 = (C0 >> 1) - 2;

    // Load 36x36 input tile, clamp-to-edge (matches jnp.clip(pos,0,n-1)).
    for (int idx = t; idx < IT * IT; idx += 256) {
        int r  = idx / IT;
        int cc = idx - r * IT;
        int gr = min(max(rin0 + r, 0), 255);
        int gc = min(max(cin0 + cc, 0), 255);
        sIn[r][cc] = src[gr * 256 + gc];
    }
    __syncthreads();

    // Horizontal upsample: thread (g = t&15, rows t>>4 step 16) produces
    // output cols 4g..4g+3 of sT from sIn cols 2g..2g+5, one b128 write.
    {
        const int g = t & 15;
        for (int r = t >> 4; r < IT; r += 16) {
            float x0 = sIn[r][2 * g + 0];
            float x1 = sIn[r][2 * g + 1];
            float x2 = sIn[r][2 * g + 2];
            float x3 = sIn[r][2 * g + 3];
            float x4 = sIn[r][2 * g + 4];
            float x5 = sIn[r][2 * g + 5];
            float4 v;
            v.x = W0 * x0 + W1 * x1 + W2 * x2 + W3 * x3;  // even col 4g
            v.y = W3 * x1 + W2 * x2 + W1 * x3 + W0 * x4;  // odd  col 4g+1
            v.z = W0 * x1 + W1 * x2 + W2 * x3 + W3 * x4;  // even col 4g+2
            v.w = W3 * x2 + W2 * x3 + W1 * x4 + W0 * x5;  // odd  col 4g+3
            *(float4*)&sT[r][4 * g] = v;
        }
    }
    __syncthreads();

    // Vertical upsample: thread (g = t&15, row-slot rs = t>>4) handles output
    // rows rs, rs+16, rs+32, rs+48 at cols 4g..4g+3. Row parity is constant
    // per thread, so phase weights hoist out of the loop.
    const int g  = t & 15;
    const int rs = t >> 4;
    const int od = rs & 1;
    const int b0 = (rs >> 1) + od;
    const float a0 = od ? W3 : W0;
    const float a1 = od ? W2 : W1;
    const float a2 = od ? W1 : W2;
    const float a3 = od ? W0 : W3;

    float mn = 1e30f, mx = -1e30f;
    float sub = 0.f, scl = 1.f;
    if (MODE == 1) { sub = res[0]; scl = res[1]; }
    float* dst = out + (size_t)pl * (512 * 512)
               + (size_t)(R0 + rs) * 512 + C0 + 4 * g;

#pragma unroll
    for (int it = 0; it < 4; ++it) {
        const int base = b0 + 8 * it;
        float4 q0 = *(const float4*)&sT[base + 0][4 * g];
        float4 q1 = *(const float4*)&sT[base + 1][4 * g];
        float4 q2 = *(const float4*)&sT[base + 2][4 * g];
        float4 q3 = *(const float4*)&sT[base + 3][4 * g];
        float4 v;
        v.x = a0 * q0.x + a1 * q1.x + a2 * q2.x + a3 * q3.x;
        v.y = a0 * q0.y + a1 * q1.y + a2 * q2.y + a3 * q3.y;
        v.z = a0 * q0.z + a1 * q1.z + a2 * q2.z + a3 * q3.z;
        v.w = a0 * q0.w + a1 * q1.w + a2 * q2.w + a3 * q3.w;
        if (MODE == 0) {
            mn = fminf(mn, fminf(fminf(v.x, v.y), fminf(v.z, v.w)));
            mx = fmaxf(mx, fmaxf(fmaxf(v.x, v.y), fmaxf(v.z, v.w)));
        } else {
            float4 o;
            o.x = (v.x - sub) * scl;
            o.y = (v.y - sub) * scl;
            o.z = (v.z - sub) * scl;
            o.w = (v.w - sub) * scl;
            *(float4*)(dst + (size_t)(16 * it) * 512) = o;
        }
    }

    if (MODE == 0) {
        for (int off = 32; off > 0; off >>= 1) {
            mn = fminf(mn, __shfl_down(mn, off, 64));
            mx = fmaxf(mx, __shfl_down(mx, off, 64));
        }
        __shared__ float wmn[4], wmx[4];
        const int wv = t >> 6;
        if ((t & 63) == 0) { wmn[wv] = mn; wmx[wv] = mx; }
        __syncthreads();
        if (t == 0) {
            float m = fminf(fminf(wmn[0], wmn[1]), fminf(wmn[2], wmn[3]));
            float M = fmaxf(fmaxf(wmx[0], wmx[1]), fmaxf(wmx[2], wmx[3]));
            const int p = (pl * 8 + ty) * 8 + tx;
            pmin[p] = m;
            pmax[p] = M;
        }
    }
}

// Single-block reduce of 4096 per-block partials -> res[0]=min, res[1]=1/(max-min).
__global__ __launch_bounds__(256)
void qwt_reduce(const float* __restrict__ pmin,
                const float* __restrict__ pmax,
                float* __restrict__ res)
{
    const int t = threadIdx.x;
    float mn = 1e30f, mx = -1e30f;
    for (int i = t; i < 4096; i += 256) {
        mn = fminf(mn, pmin[i]);
        mx = fmaxf(mx, pmax[i]);
    }
    for (int off = 32; off > 0; off >>= 1) {
        mn = fminf(mn, __shfl_down(mn, off, 64));
        mx = fmaxf(mx, __shfl_down(mx, off, 64));
    }
    __shared__ float wmn[4], wmx[4];
    const int wv = t >> 6;
    if ((t & 63) == 0) { wmn[wv] = mn; wmx[wv] = mx; }
    __syncthreads();
    if (t == 0) {
        float m = fminf(fminf(wmn[0], wmn[1]), fminf(wmn[2], wmn[3]));
        float M = fmaxf(fmaxf(wmx[0], wmx[1]), fmaxf(wmx[2], wmx[3]));
        res[0] = m;
        res[1] = 1.0f / (M - m);
    }
}

extern "C" void kernel_launch(void* const* d_in, const int* in_sizes, int n_in,
                              void* d_out, int out_size, void* d_ws, size_t ws_size,
                              hipStream_t stream)
{
    (void)in_sizes; (void)n_in; (void)out_size; (void)ws_size;
    const float* LL = (const float*)d_in[0];
    float* out      = (float*)d_out;

    // ws layout: [0,4096) per-block mins, [4096,8192) per-block maxs,
    // [8192,8194) final (min, 1/(max-min)). All written before read — no init
    // needed despite 0xAA poison.
    float* pmin = (float*)d_ws;
    float* pmax = pmin + 4096;
    float* res  = pmin + 8192;

    dim3 grid(8, 8, 64);
    dim3 block(256);
    qwt_up2<0><<<grid, block, 0, stream>>>(LL, nullptr, pmin, pmax, nullptr);
    qwt_reduce<<<dim3(1), block, 0, stream>>>(pmin, pmax, res);
    qwt_up2<1><<<grid, block, 0, stream>>>(LL, out, nullptr, nullptr, res);
}